// Round 2
// baseline (1453.864 us; speedup 1.0000x reference)
//
#include <hip/hip_runtime.h>

// GAT 3-layer: GATConv(128->64)+BN+ReLU -> GATConv(64->64)+BN+ReLU -> GATConv(64->32)
// fp32 everywhere. N=100000 nodes, E=1600000 edges (+N self loops).

#define D_IN 128
#define EPS 1e-5f
#define SLOPE 0.2f

// ---------------------------------------------------------------------------
// GEMM H = X[n,K] @ W[K,F], fused epilogue: HS = H·a_s, HD = H·a_d per row.
// Block: 256 threads, 64 rows/block, full F width. LDS: X tile + W.
// Thread (tr,tc) = (tid/16, tid%16) computes rows {tr+16i} x cols {tc*CPT..}.
// ---------------------------------------------------------------------------
template <int K, int F>
__global__ __launch_bounds__(256) void gemm_scores(
    const float* __restrict__ X, const float* __restrict__ W,
    const float* __restrict__ a_s, const float* __restrict__ a_d,
    float* __restrict__ H, float* __restrict__ HS, float* __restrict__ HD,
    int n)
{
    // pad X tile stride unless it would push LDS past 64 KB (K=128 case)
    constexpr int XS  = (K == 128) ? K : (K + 4);
    constexpr int CPT = F / 16;                 // cols per thread
    __shared__ float Xs[64 * XS];
    __shared__ float Ws[K * F];

    const int tid  = threadIdx.x;
    const int row0 = blockIdx.x * 64;

    // stage X tile (64 rows x K), float4, coalesced (tile is contiguous in X)
    for (int i = tid * 4; i < 64 * K; i += 256 * 4) {
        int row = i / K, col = i % K;
        float4 v = make_float4(0.f, 0.f, 0.f, 0.f);
        if (row0 + row < n)
            v = *(const float4*)&X[(size_t)(row0 + row) * K + col];
        *(float4*)&Xs[row * XS + col] = v;
    }
    // stage W (K x F)
    for (int i = tid; i < K * F / 4; i += 256)
        *(float4*)&Ws[i * 4] = ((const float4*)W)[i];
    __syncthreads();

    const int tr = tid >> 4, tc = tid & 15;
    float acc[4][CPT];
    #pragma unroll
    for (int i = 0; i < 4; i++)
        #pragma unroll
        for (int j = 0; j < CPT; j++) acc[i][j] = 0.f;

    for (int k = 0; k < K; k += 4) {
        float xv[4][4];
        #pragma unroll
        for (int i = 0; i < 4; i++) {
            float4 t = *(const float4*)&Xs[(tr + 16 * i) * XS + k];
            xv[i][0] = t.x; xv[i][1] = t.y; xv[i][2] = t.z; xv[i][3] = t.w;
        }
        #pragma unroll
        for (int kk = 0; kk < 4; kk++) {
            float wv[CPT];
            if constexpr (CPT == 4) {
                float4 t = *(const float4*)&Ws[(k + kk) * F + tc * 4];
                wv[0] = t.x; wv[1] = t.y; wv[2] = t.z; wv[3] = t.w;
            } else {
                float2 t = *(const float2*)&Ws[(k + kk) * F + tc * 2];
                wv[0] = t.x; wv[1] = t.y;
            }
            #pragma unroll
            for (int i = 0; i < 4; i++)
                #pragma unroll
                for (int j = 0; j < CPT; j++)
                    acc[i][j] += xv[i][kk] * wv[j];
        }
    }

    // epilogue: store H rows + fused score dots (reduce over 16 tc lanes)
    float cs[CPT], cd[CPT];
    #pragma unroll
    for (int j = 0; j < CPT; j++) {
        cs[j] = a_s[tc * CPT + j];
        cd[j] = a_d[tc * CPT + j];
    }
    #pragma unroll
    for (int i = 0; i < 4; i++) {
        int row = row0 + tr + 16 * i;
        float vs = 0.f, vd = 0.f;
        #pragma unroll
        for (int j = 0; j < CPT; j++) { vs += acc[i][j] * cs[j]; vd += acc[i][j] * cd[j]; }
        #pragma unroll
        for (int m = 1; m < 16; m <<= 1) {
            vs += __shfl_xor(vs, m, 64);
            vd += __shfl_xor(vd, m, 64);
        }
        if (row < n) {
            if constexpr (CPT == 4) {
                float4 t = make_float4(acc[i][0], acc[i][1], acc[i][2], acc[i][3]);
                *(float4*)&H[(size_t)row * F + tc * 4] = t;
            } else {
                float2 t = make_float2(acc[i][0], acc[i][1]);
                *(float2*)&H[(size_t)row * F + tc * 2] = t;
            }
            if (tc == 0) { HS[row] = vs; HD[row] = vd; }
        }
    }
}

// ---------------------------------------------------------------------------
// Edge pass 1: p = exp(leaky_relu(hs[src]+hd[dst])); s[dst] += p
// (global max subtraction skipped: alpha is invariant, scores are O(8) max)
// ---------------------------------------------------------------------------
__global__ __launch_bounds__(256) void edge_softmax_p(
    const int* __restrict__ src, const int* __restrict__ dst,
    const float* __restrict__ HS, const float* __restrict__ HD,
    float* __restrict__ P, float* __restrict__ S, int E, int n)
{
    int e = blockIdx.x * 256 + threadIdx.x;
    int ET = E + n;
    if (e >= ET) return;
    int s_, d_;
    if (e < E) { s_ = src[e]; d_ = dst[e]; }
    else       { s_ = d_ = e - E; }          // self loop
    float sc = HS[s_] + HD[d_];
    sc = sc > 0.f ? sc : SLOPE * sc;
    float pe = expf(sc);
    P[e] = pe;
    atomicAdd(&S[d_], pe);
}

// ---------------------------------------------------------------------------
// Edge pass 2 (heavy): out[dst,:] += h[src,:] * (p[e]/s[dst])
// F lanes per edge; row gather + per-feature atomicAdd, both coalesced.
// ---------------------------------------------------------------------------
template <int F>
__global__ __launch_bounds__(256) void edge_aggregate(
    const int* __restrict__ src, const int* __restrict__ dst,
    const float* __restrict__ H, const float* __restrict__ P,
    const float* __restrict__ S, float* __restrict__ OUT, int E, int n)
{
    int t = blockIdx.x * 256 + threadIdx.x;
    int e = t / F;
    int f = t % F;
    int ET = E + n;
    if (e >= ET) return;
    int s_, d_;
    if (e < E) { s_ = src[e]; d_ = dst[e]; }
    else       { s_ = d_ = e - E; }
    float alpha = P[e] / S[d_];
    atomicAdd(&OUT[(size_t)d_ * F + f], H[(size_t)s_ * F + f] * alpha);
}

// ---------------------------------------------------------------------------
// Fused bias + BatchNorm(eval) + ReLU, in place.
// ---------------------------------------------------------------------------
template <int F>
__global__ __launch_bounds__(256) void bias_bn_relu(
    float* __restrict__ X, const float* __restrict__ b,
    const float* __restrict__ g, const float* __restrict__ be,
    const float* __restrict__ rm, const float* __restrict__ rv, int n)
{
    int idx = blockIdx.x * 256 + threadIdx.x;
    if (idx >= n * F) return;
    int f = idx & (F - 1);
    float v = X[idx] + b[f];
    v = (v - rm[f]) * rsqrtf(rv[f] + EPS) * g[f] + be[f];
    X[idx] = v > 0.f ? v : 0.f;
}

__global__ __launch_bounds__(256) void add_bias(
    float* __restrict__ O, const float* __restrict__ b, int total, int F)
{
    int idx = blockIdx.x * 256 + threadIdx.x;
    if (idx >= total) return;
    O[idx] += b[idx % F];
}

// ---------------------------------------------------------------------------
extern "C" void kernel_launch(void* const* d_in, const int* in_sizes, int n_in,
                              void* d_out, int out_size, void* d_ws, size_t ws_size,
                              hipStream_t stream)
{
    const float* x   = (const float*)d_in[0];
    const int*   ei  = (const int*)d_in[1];
    const float* W1  = (const float*)d_in[2];
    const float* as1 = (const float*)d_in[3];
    const float* ad1 = (const float*)d_in[4];
    const float* b1  = (const float*)d_in[5];
    const float* g1  = (const float*)d_in[6];
    const float* be1 = (const float*)d_in[7];
    const float* rm1 = (const float*)d_in[8];
    const float* rv1 = (const float*)d_in[9];
    const float* W2  = (const float*)d_in[10];
    const float* as2 = (const float*)d_in[11];
    const float* ad2 = (const float*)d_in[12];
    const float* b2  = (const float*)d_in[13];
    const float* g2  = (const float*)d_in[14];
    const float* be2 = (const float*)d_in[15];
    const float* rm2 = (const float*)d_in[16];
    const float* rv2 = (const float*)d_in[17];
    const float* W3  = (const float*)d_in[18];
    const float* as3 = (const float*)d_in[19];
    const float* ad3 = (const float*)d_in[20];
    const float* b3  = (const float*)d_in[21];

    const int n  = in_sizes[0] / D_IN;   // 100000
    const int E  = in_sizes[1] / 2;      // 1600000
    const int ET = E + n;                // with self loops
    const int* src = ei;
    const int* dst = ei + E;

    // workspace layout (floats)
    float* ws = (float*)d_ws;
    float* H   = ws;                        // n*64  (per-layer h; layer3 uses n*32)
    float* X2  = H  + (size_t)n * 64;       // n*64  (layer input / agg buffer)
    float* P   = X2 + (size_t)n * 64;       // ET
    float* S   = P  + ET;                   // n
    float* HS  = S  + n;                    // n
    float* HD  = HS + n;                    // n

    const int gemm_grid = (n + 63) / 64;
    const int ep_grid   = (ET + 255) / 256;
    const int ea64_grid = (int)(((size_t)ET * 64 + 255) / 256);
    const int ea32_grid = (int)(((size_t)ET * 32 + 255) / 256);
    const int nf64_grid = (n * 64 + 255) / 256;
    const int nf32_grid = (n * 32 + 255) / 256;

    // ---------------- Layer 1: GATConv(128->64) + BN + ReLU ----------------
    gemm_scores<128, 64><<<gemm_grid, 256, 0, stream>>>(x, W1, as1, ad1, H, HS, HD, n);
    hipMemsetAsync(S, 0, (size_t)n * 4, stream);
    hipMemsetAsync(X2, 0, (size_t)n * 64 * 4, stream);
    edge_softmax_p<<<ep_grid, 256, 0, stream>>>(src, dst, HS, HD, P, S, E, n);
    edge_aggregate<64><<<ea64_grid, 256, 0, stream>>>(src, dst, H, P, S, X2, E, n);
    bias_bn_relu<64><<<nf64_grid, 256, 0, stream>>>(X2, b1, g1, be1, rm1, rv1, n);

    // ---------------- Layer 2: GATConv(64->64) + BN + ReLU ------------------
    gemm_scores<64, 64><<<gemm_grid, 256, 0, stream>>>(X2, W2, as2, ad2, H, HS, HD, n);
    hipMemsetAsync(S, 0, (size_t)n * 4, stream);
    // X2 consumed by gemm above; reuse as aggregation buffer (stream-ordered)
    hipMemsetAsync(X2, 0, (size_t)n * 64 * 4, stream);
    edge_softmax_p<<<ep_grid, 256, 0, stream>>>(src, dst, HS, HD, P, S, E, n);
    edge_aggregate<64><<<ea64_grid, 256, 0, stream>>>(src, dst, H, P, S, X2, E, n);
    bias_bn_relu<64><<<nf64_grid, 256, 0, stream>>>(X2, b2, g2, be2, rm2, rv2, n);

    // ---------------- Layer 3: GATConv(64->32) ------------------------------
    gemm_scores<64, 32><<<gemm_grid, 256, 0, stream>>>(X2, W3, as3, ad3, H, HS, HD, n);
    hipMemsetAsync(S, 0, (size_t)n * 4, stream);
    hipMemsetAsync(d_out, 0, (size_t)n * 32 * 4, stream);
    edge_softmax_p<<<ep_grid, 256, 0, stream>>>(src, dst, HS, HD, P, S, E, n);
    edge_aggregate<32><<<ea32_grid, 256, 0, stream>>>(src, dst, H, P, S, (float*)d_out, E, n);
    add_bias<<<nf32_grid, 256, 0, stream>>>((float*)d_out, b3, n * 32, 32);
}

// Round 10
// 799.417 us; speedup vs baseline: 1.8187x; 1.8187x over previous
//
#include <hip/hip_runtime.h>

// GAT 3-layer: GATConv(128->64)+BN+ReLU -> GATConv(64->64)+BN+ReLU -> GATConv(64->32)
// fp32. N=100000, E=1600000 (+N implicit self loops).
//
// CSR-by-dst built once per launch (hist/scan/scatter), then per-layer:
// GEMM(+fused score dots) -> gat_aggregate (register accumulation per node
// segment, softmax on the fly, fused bias+BN+ReLU, ZERO float atomics).
// Round-2 rocprof showed 425MB/dispatch atomic write-through (WRITE_SIZE) on
// edge_aggregate — this structure removes it.

#define D_IN 128
#define EPS 1e-5f
#define SLOPE 0.2f

// ---------------------------------------------------------------------------
// GEMM H = X[n,K] @ W[K,F], fused epilogue: HS = H·a_s, HD = H·a_d per row.
// ---------------------------------------------------------------------------
template <int K, int F>
__global__ __launch_bounds__(256) void gemm_scores(
    const float* __restrict__ X, const float* __restrict__ W,
    const float* __restrict__ a_s, const float* __restrict__ a_d,
    float* __restrict__ H, float* __restrict__ HS, float* __restrict__ HD,
    int n)
{
    constexpr int XS  = (K == 128) ? K : (K + 4);
    constexpr int CPT = F / 16;
    __shared__ float Xs[64 * XS];
    __shared__ float Ws[K * F];

    const int tid  = threadIdx.x;
    const int row0 = blockIdx.x * 64;

    for (int i = tid * 4; i < 64 * K; i += 256 * 4) {
        int row = i / K, col = i % K;
        float4 v = make_float4(0.f, 0.f, 0.f, 0.f);
        if (row0 + row < n)
            v = *(const float4*)&X[(size_t)(row0 + row) * K + col];
        *(float4*)&Xs[row * XS + col] = v;
    }
    for (int i = tid; i < K * F / 4; i += 256)
        *(float4*)&Ws[i * 4] = ((const float4*)W)[i];
    __syncthreads();

    const int tr = tid >> 4, tc = tid & 15;
    float acc[4][CPT];
    #pragma unroll
    for (int i = 0; i < 4; i++)
        #pragma unroll
        for (int j = 0; j < CPT; j++) acc[i][j] = 0.f;

    for (int k = 0; k < K; k += 4) {
        float xv[4][4];
        #pragma unroll
        for (int i = 0; i < 4; i++) {
            float4 t = *(const float4*)&Xs[(tr + 16 * i) * XS + k];
            xv[i][0] = t.x; xv[i][1] = t.y; xv[i][2] = t.z; xv[i][3] = t.w;
        }
        #pragma unroll
        for (int kk = 0; kk < 4; kk++) {
            float wv[CPT];
            if constexpr (CPT == 4) {
                float4 t = *(const float4*)&Ws[(k + kk) * F + tc * 4];
                wv[0] = t.x; wv[1] = t.y; wv[2] = t.z; wv[3] = t.w;
            } else {
                float2 t = *(const float2*)&Ws[(k + kk) * F + tc * 2];
                wv[0] = t.x; wv[1] = t.y;
            }
            #pragma unroll
            for (int i = 0; i < 4; i++)
                #pragma unroll
                for (int j = 0; j < CPT; j++)
                    acc[i][j] += xv[i][kk] * wv[j];
        }
    }

    float cs[CPT], cd[CPT];
    #pragma unroll
    for (int j = 0; j < CPT; j++) {
        cs[j] = a_s[tc * CPT + j];
        cd[j] = a_d[tc * CPT + j];
    }
    #pragma unroll
    for (int i = 0; i < 4; i++) {
        int row = row0 + tr + 16 * i;
        float vs = 0.f, vd = 0.f;
        #pragma unroll
        for (int j = 0; j < CPT; j++) { vs += acc[i][j] * cs[j]; vd += acc[i][j] * cd[j]; }
        #pragma unroll
        for (int m = 1; m < 16; m <<= 1) {
            vs += __shfl_xor(vs, m, 64);
            vd += __shfl_xor(vd, m, 64);
        }
        if (row < n) {
            if constexpr (CPT == 4) {
                float4 t = make_float4(acc[i][0], acc[i][1], acc[i][2], acc[i][3]);
                *(float4*)&H[(size_t)row * F + tc * 4] = t;
            } else {
                float2 t = make_float2(acc[i][0], acc[i][1]);
                *(float2*)&H[(size_t)row * F + tc * 2] = t;
            }
            if (tc == 0) { HS[row] = vs; HD[row] = vd; }
        }
    }
}

// ---------------------------------------------------------------------------
// CSR build: in-degree histogram -> exclusive scan -> scatter src by dst.
// ---------------------------------------------------------------------------
__global__ __launch_bounds__(256) void hist_kernel(
    const int* __restrict__ dst, int* __restrict__ deg, int E)
{
    int e = blockIdx.x * 256 + threadIdx.x;
    if (e < E) atomicAdd(&deg[dst[e]], 1);
}

__global__ __launch_bounds__(512) void scan_phase1(
    const int* __restrict__ deg, int* __restrict__ rowptr,
    int* __restrict__ sums, int n)
{
    __shared__ int s[512];
    int t = threadIdx.x;
    int i = blockIdx.x * 512 + t;
    int v = (i < n) ? deg[i] : 0;
    s[t] = v;
    __syncthreads();
    for (int off = 1; off < 512; off <<= 1) {
        int x = (t >= off) ? s[t - off] : 0;
        __syncthreads();
        s[t] += x;
        __syncthreads();
    }
    if (i < n) rowptr[i] = s[t] - v;              // exclusive within chunk
    if (t == 511) sums[blockIdx.x] = s[511];      // chunk total
}

__global__ __launch_bounds__(512) void scan_phase2(int* __restrict__ sums, int nb)
{
    __shared__ int s[512];
    int t = threadIdx.x;
    int v = (t < nb) ? sums[t] : 0;
    s[t] = v;
    __syncthreads();
    for (int off = 1; off < 512; off <<= 1) {
        int x = (t >= off) ? s[t - off] : 0;
        __syncthreads();
        s[t] += x;
        __syncthreads();
    }
    if (t < nb) sums[t] = s[t] - v;               // exclusive chunk offsets
}

__global__ __launch_bounds__(256) void scan_phase3(
    int* __restrict__ rowptr, const int* __restrict__ sums, int n, int E)
{
    int i = blockIdx.x * 256 + threadIdx.x;
    if (i < n) rowptr[i] += sums[i >> 9];
    else if (i == n) rowptr[n] = E;
}

__global__ __launch_bounds__(256) void scatter_kernel(
    const int* __restrict__ src, const int* __restrict__ dst,
    const int* __restrict__ rowptr, int* __restrict__ cnt,
    int* __restrict__ esrc, int E)
{
    int e = blockIdx.x * 256 + threadIdx.x;
    if (e >= E) return;
    int d = dst[e];
    int slot = rowptr[d] + atomicAdd(&cnt[d], 1);
    esrc[slot] = src[e];
}

// ---------------------------------------------------------------------------
// Fused GAT aggregation: per node, loop over CSR in-edge segment.
//   p computed on the fly (softmax max-shift skipped: alpha invariant, scores
//   bounded ~|8| here), self-loop seeds the accumulator, epilogue fuses
//   bias (+ BN + ReLU when BN=true). F lanes per node, register accumulation,
//   plain stores — zero float atomics.
// ---------------------------------------------------------------------------
template <int F, bool BN>
__global__ __launch_bounds__(256) void gat_aggregate(
    const int* __restrict__ rowptr, const int* __restrict__ esrc,
    const float* __restrict__ H, const float* __restrict__ HS,
    const float* __restrict__ HD,
    const float* __restrict__ b, const float* __restrict__ g,
    const float* __restrict__ be, const float* __restrict__ rm,
    const float* __restrict__ rv,
    float* __restrict__ OUT, int n)
{
    int t = blockIdx.x * 256 + threadIdx.x;
    int node = t / F, f = t % F;          // F is a power of two -> shifts
    if (node >= n) return;

    float hd = HD[node];
    // self loop
    float sc = HS[node] + hd;
    sc = sc > 0.f ? sc : SLOPE * sc;
    float p = __expf(sc);
    float s = p;
    float acc = p * H[(size_t)node * F + f];

    int beg = rowptr[node], end = rowptr[node + 1];
    for (int j = beg; j < end; ++j) {
        int sr = esrc[j];
        float sc2 = HS[sr] + hd;
        sc2 = sc2 > 0.f ? sc2 : SLOPE * sc2;
        float p2 = __expf(sc2);
        s += p2;
        acc += p2 * H[(size_t)sr * F + f];
    }

    float v = acc / s + b[f];
    if constexpr (BN) {
        v = (v - rm[f]) * rsqrtf(rv[f] + EPS) * g[f] + be[f];
        v = v > 0.f ? v : 0.f;
    }
    OUT[(size_t)node * F + f] = v;
}

// ---------------------------------------------------------------------------
extern "C" void kernel_launch(void* const* d_in, const int* in_sizes, int n_in,
                              void* d_out, int out_size, void* d_ws, size_t ws_size,
                              hipStream_t stream)
{
    const float* x   = (const float*)d_in[0];
    const int*   ei  = (const int*)d_in[1];
    const float* W1  = (const float*)d_in[2];
    const float* as1 = (const float*)d_in[3];
    const float* ad1 = (const float*)d_in[4];
    const float* b1  = (const float*)d_in[5];
    const float* g1  = (const float*)d_in[6];
    const float* be1 = (const float*)d_in[7];
    const float* rm1 = (const float*)d_in[8];
    const float* rv1 = (const float*)d_in[9];
    const float* W2  = (const float*)d_in[10];
    const float* as2 = (const float*)d_in[11];
    const float* ad2 = (const float*)d_in[12];
    const float* b2  = (const float*)d_in[13];
    const float* g2  = (const float*)d_in[14];
    const float* be2 = (const float*)d_in[15];
    const float* rm2 = (const float*)d_in[16];
    const float* rv2 = (const float*)d_in[17];
    const float* W3  = (const float*)d_in[18];
    const float* as3 = (const float*)d_in[19];
    const float* ad3 = (const float*)d_in[20];
    const float* b3  = (const float*)d_in[21];

    const int n  = in_sizes[0] / D_IN;   // 100000
    const int E  = in_sizes[1] / 2;      // 1600000
    const int* src = ei;
    const int* dst = ei + E;

    // workspace layout
    float* ws = (float*)d_ws;
    float* H      = ws;                          // n*64 floats (layer3 uses n*32)
    float* X2     = H  + (size_t)n * 64;         // n*64 floats
    float* HS     = X2 + (size_t)n * 64;         // n
    float* HD     = HS + n;                      // n
    int*   deg    = (int*)(HD + n);              // n
    int*   cnt    = deg + n;                     // n
    int*   rowptr = cnt + n;                     // n+1
    int*   sums   = rowptr + (n + 1);            // 512
    int*   esrc   = sums + 512;                  // E

    const int NB = (n + 511) / 512;              // scan chunks (196)

    // ---- CSR build (once; graph identical for all 3 layers) ----
    hipMemsetAsync(deg, 0, (size_t)n * 4, stream);
    hipMemsetAsync(cnt, 0, (size_t)n * 4, stream);
    hist_kernel<<<(E + 255) / 256, 256, 0, stream>>>(dst, deg, E);
    scan_phase1<<<NB, 512, 0, stream>>>(deg, rowptr, sums, n);
    scan_phase2<<<1, 512, 0, stream>>>(sums, NB);
    scan_phase3<<<(n + 256) / 256, 256, 0, stream>>>(rowptr, sums, n, E);
    scatter_kernel<<<(E + 255) / 256, 256, 0, stream>>>(src, dst, rowptr, cnt, esrc, E);

    const int gemm_grid = (n + 63) / 64;
    const int ag64_grid = (int)(((size_t)n * 64 + 255) / 256);
    const int ag32_grid = (int)(((size_t)n * 32 + 255) / 256);

    // ---- Layer 1: GATConv(128->64) + BN + ReLU ----
    gemm_scores<128, 64><<<gemm_grid, 256, 0, stream>>>(x, W1, as1, ad1, H, HS, HD, n);
    gat_aggregate<64, true><<<ag64_grid, 256, 0, stream>>>(
        rowptr, esrc, H, HS, HD, b1, g1, be1, rm1, rv1, X2, n);

    // ---- Layer 2: GATConv(64->64) + BN + ReLU ----
    gemm_scores<64, 64><<<gemm_grid, 256, 0, stream>>>(X2, W2, as2, ad2, H, HS, HD, n);
    gat_aggregate<64, true><<<ag64_grid, 256, 0, stream>>>(
        rowptr, esrc, H, HS, HD, b2, g2, be2, rm2, rv2, X2, n);

    // ---- Layer 3: GATConv(64->32), bias only ----
    gemm_scores<64, 32><<<gemm_grid, 256, 0, stream>>>(X2, W3, as3, ad3, H, HS, HD, n);
    gat_aggregate<32, false><<<ag32_grid, 256, 0, stream>>>(
        rowptr, esrc, H, HS, HD, b3, nullptr, nullptr, nullptr, nullptr,
        (float*)d_out, n);
}

// Round 11
// 588.548 us; speedup vs baseline: 2.4703x; 1.3583x over previous
//
#include <hip/hip_runtime.h>

// GAT 3-layer: GATConv(128->64)+BN+ReLU -> GATConv(64->64)+BN+ReLU -> GATConv(64->32)
// fp32. N=100000, E=1600000 (+N implicit self loops).
//
// CSR-by-dst built once per launch; per-layer GEMM(+score dots) ->
// gat_aggregate (register accumulation, softmax on the fly, fused BN/ReLU).
// R10 counters: aggregate latency-bound (VALUBusy 31%, VGPR=12, 1 outstanding
// gather). This round: segment loop unrolled x4 -> 4 gathers in flight.

#define D_IN 128
#define EPS 1e-5f
#define SLOPE 0.2f

// ---------------------------------------------------------------------------
// GEMM H = X[n,K] @ W[K,F], fused epilogue: HS = H·a_s, HD = H·a_d per row.
// ---------------------------------------------------------------------------
template <int K, int F>
__global__ __launch_bounds__(256) void gemm_scores(
    const float* __restrict__ X, const float* __restrict__ W,
    const float* __restrict__ a_s, const float* __restrict__ a_d,
    float* __restrict__ H, float* __restrict__ HS, float* __restrict__ HD,
    int n)
{
    constexpr int XS  = (K == 128) ? K : (K + 4);
    constexpr int CPT = F / 16;
    __shared__ float Xs[64 * XS];
    __shared__ float Ws[K * F];

    const int tid  = threadIdx.x;
    const int row0 = blockIdx.x * 64;

    for (int i = tid * 4; i < 64 * K; i += 256 * 4) {
        int row = i / K, col = i % K;
        float4 v = make_float4(0.f, 0.f, 0.f, 0.f);
        if (row0 + row < n)
            v = *(const float4*)&X[(size_t)(row0 + row) * K + col];
        *(float4*)&Xs[row * XS + col] = v;
    }
    for (int i = tid; i < K * F / 4; i += 256)
        *(float4*)&Ws[i * 4] = ((const float4*)W)[i];
    __syncthreads();

    const int tr = tid >> 4, tc = tid & 15;
    float acc[4][CPT];
    #pragma unroll
    for (int i = 0; i < 4; i++)
        #pragma unroll
        for (int j = 0; j < CPT; j++) acc[i][j] = 0.f;

    for (int k = 0; k < K; k += 4) {
        float xv[4][4];
        #pragma unroll
        for (int i = 0; i < 4; i++) {
            float4 t = *(const float4*)&Xs[(tr + 16 * i) * XS + k];
            xv[i][0] = t.x; xv[i][1] = t.y; xv[i][2] = t.z; xv[i][3] = t.w;
        }
        #pragma unroll
        for (int kk = 0; kk < 4; kk++) {
            float wv[CPT];
            if constexpr (CPT == 4) {
                float4 t = *(const float4*)&Ws[(k + kk) * F + tc * 4];
                wv[0] = t.x; wv[1] = t.y; wv[2] = t.z; wv[3] = t.w;
            } else {
                float2 t = *(const float2*)&Ws[(k + kk) * F + tc * 2];
                wv[0] = t.x; wv[1] = t.y;
            }
            #pragma unroll
            for (int i = 0; i < 4; i++)
                #pragma unroll
                for (int j = 0; j < CPT; j++)
                    acc[i][j] += xv[i][kk] * wv[j];
        }
    }

    float cs[CPT], cd[CPT];
    #pragma unroll
    for (int j = 0; j < CPT; j++) {
        cs[j] = a_s[tc * CPT + j];
        cd[j] = a_d[tc * CPT + j];
    }
    #pragma unroll
    for (int i = 0; i < 4; i++) {
        int row = row0 + tr + 16 * i;
        float vs = 0.f, vd = 0.f;
        #pragma unroll
        for (int j = 0; j < CPT; j++) { vs += acc[i][j] * cs[j]; vd += acc[i][j] * cd[j]; }
        #pragma unroll
        for (int m = 1; m < 16; m <<= 1) {
            vs += __shfl_xor(vs, m, 64);
            vd += __shfl_xor(vd, m, 64);
        }
        if (row < n) {
            if constexpr (CPT == 4) {
                float4 t = make_float4(acc[i][0], acc[i][1], acc[i][2], acc[i][3]);
                *(float4*)&H[(size_t)row * F + tc * 4] = t;
            } else {
                float2 t = make_float2(acc[i][0], acc[i][1]);
                *(float2*)&H[(size_t)row * F + tc * 2] = t;
            }
            if (tc == 0) { HS[row] = vs; HD[row] = vd; }
        }
    }
}

// ---------------------------------------------------------------------------
// CSR build: in-degree histogram -> exclusive scan -> scatter src by dst.
// ---------------------------------------------------------------------------
__global__ __launch_bounds__(256) void hist_kernel(
    const int* __restrict__ dst, int* __restrict__ deg, int E)
{
    int e = blockIdx.x * 256 + threadIdx.x;
    if (e < E) atomicAdd(&deg[dst[e]], 1);
}

__global__ __launch_bounds__(512) void scan_phase1(
    const int* __restrict__ deg, int* __restrict__ rowptr,
    int* __restrict__ sums, int n)
{
    __shared__ int s[512];
    int t = threadIdx.x;
    int i = blockIdx.x * 512 + t;
    int v = (i < n) ? deg[i] : 0;
    s[t] = v;
    __syncthreads();
    for (int off = 1; off < 512; off <<= 1) {
        int x = (t >= off) ? s[t - off] : 0;
        __syncthreads();
        s[t] += x;
        __syncthreads();
    }
    if (i < n) rowptr[i] = s[t] - v;              // exclusive within chunk
    if (t == 511) sums[blockIdx.x] = s[511];      // chunk total
}

__global__ __launch_bounds__(512) void scan_phase2(int* __restrict__ sums, int nb)
{
    __shared__ int s[512];
    int t = threadIdx.x;
    int v = (t < nb) ? sums[t] : 0;
    s[t] = v;
    __syncthreads();
    for (int off = 1; off < 512; off <<= 1) {
        int x = (t >= off) ? s[t - off] : 0;
        __syncthreads();
        s[t] += x;
        __syncthreads();
    }
    if (t < nb) sums[t] = s[t] - v;               // exclusive chunk offsets
}

__global__ __launch_bounds__(256) void scan_phase3(
    int* __restrict__ rowptr, const int* __restrict__ sums, int n, int E)
{
    int i = blockIdx.x * 256 + threadIdx.x;
    if (i < n) rowptr[i] += sums[i >> 9];
    else if (i == n) rowptr[n] = E;
}

__global__ __launch_bounds__(256) void scatter_kernel(
    const int* __restrict__ src, const int* __restrict__ dst,
    const int* __restrict__ rowptr, int* __restrict__ cnt,
    int* __restrict__ esrc, int E)
{
    int e = blockIdx.x * 256 + threadIdx.x;
    if (e >= E) return;
    int d = dst[e];
    int slot = rowptr[d] + atomicAdd(&cnt[d], 1);
    esrc[slot] = src[e];
}

// ---------------------------------------------------------------------------
// Fused GAT aggregation, unrolled x4 for memory-level parallelism.
//   R10 PMC: VGPR=12, VALUBusy 31% -> 1 outstanding gather per wave,
//   latency-bound. Batch 4 edges per iteration: 4 independent esrc loads,
//   4 HS broadcasts, 4 H-row gathers in flight.
// ---------------------------------------------------------------------------
template <int F, bool BN>
__global__ __launch_bounds__(256) void gat_aggregate(
    const int* __restrict__ rowptr, const int* __restrict__ esrc,
    const float* __restrict__ H, const float* __restrict__ HS,
    const float* __restrict__ HD,
    const float* __restrict__ b, const float* __restrict__ g,
    const float* __restrict__ be, const float* __restrict__ rm,
    const float* __restrict__ rv,
    float* __restrict__ OUT, int n)
{
    int t = blockIdx.x * 256 + threadIdx.x;
    int node = t / F, f = t % F;          // F is a power of two -> shifts
    if (node >= n) return;

    float hd = HD[node];
    // self loop seeds the accumulator
    float sc = HS[node] + hd;
    sc = sc > 0.f ? sc : SLOPE * sc;
    float p = __expf(sc);
    float s = p;
    float acc = p * H[(size_t)node * F + f];

    const int beg = rowptr[node], end = rowptr[node + 1];
    int j = beg;
    const int end4 = beg + ((end - beg) & ~3);

    for (; j < end4; j += 4) {
        // phase 1: 4 independent index loads
        int sr0 = esrc[j + 0];
        int sr1 = esrc[j + 1];
        int sr2 = esrc[j + 2];
        int sr3 = esrc[j + 3];
        // phase 2: 4 independent score loads + 4 row gathers (8 in flight)
        float a0 = HS[sr0];
        float a1 = HS[sr1];
        float a2 = HS[sr2];
        float a3 = HS[sr3];
        float h0 = H[(size_t)sr0 * F + f];
        float h1 = H[(size_t)sr1 * F + f];
        float h2 = H[(size_t)sr2 * F + f];
        float h3 = H[(size_t)sr3 * F + f];
        // phase 3: arithmetic
        float s0 = a0 + hd; s0 = s0 > 0.f ? s0 : SLOPE * s0;
        float s1 = a1 + hd; s1 = s1 > 0.f ? s1 : SLOPE * s1;
        float s2 = a2 + hd; s2 = s2 > 0.f ? s2 : SLOPE * s2;
        float s3 = a3 + hd; s3 = s3 > 0.f ? s3 : SLOPE * s3;
        float p0 = __expf(s0);
        float p1 = __expf(s1);
        float p2 = __expf(s2);
        float p3 = __expf(s3);
        s   += (p0 + p1) + (p2 + p3);
        acc += p0 * h0 + p1 * h1 + p2 * h2 + p3 * h3;
    }
    for (; j < end; ++j) {                 // remainder (<4 edges)
        int sr = esrc[j];
        float sc2 = HS[sr] + hd;
        sc2 = sc2 > 0.f ? sc2 : SLOPE * sc2;
        float p2 = __expf(sc2);
        s += p2;
        acc += p2 * H[(size_t)sr * F + f];
    }

    float v = acc / s + b[f];
    if constexpr (BN) {
        v = (v - rm[f]) * rsqrtf(rv[f] + EPS) * g[f] + be[f];
        v = v > 0.f ? v : 0.f;
    }
    OUT[(size_t)node * F + f] = v;
}

// ---------------------------------------------------------------------------
extern "C" void kernel_launch(void* const* d_in, const int* in_sizes, int n_in,
                              void* d_out, int out_size, void* d_ws, size_t ws_size,
                              hipStream_t stream)
{
    const float* x   = (const float*)d_in[0];
    const int*   ei  = (const int*)d_in[1];
    const float* W1  = (const float*)d_in[2];
    const float* as1 = (const float*)d_in[3];
    const float* ad1 = (const float*)d_in[4];
    const float* b1  = (const float*)d_in[5];
    const float* g1  = (const float*)d_in[6];
    const float* be1 = (const float*)d_in[7];
    const float* rm1 = (const float*)d_in[8];
    const float* rv1 = (const float*)d_in[9];
    const float* W2  = (const float*)d_in[10];
    const float* as2 = (const float*)d_in[11];
    const float* ad2 = (const float*)d_in[12];
    const float* b2  = (const float*)d_in[13];
    const float* g2  = (const float*)d_in[14];
    const float* be2 = (const float*)d_in[15];
    const float* rm2 = (const float*)d_in[16];
    const float* rv2 = (const float*)d_in[17];
    const float* W3  = (const float*)d_in[18];
    const float* as3 = (const float*)d_in[19];
    const float* ad3 = (const float*)d_in[20];
    const float* b3  = (const float*)d_in[21];

    const int n  = in_sizes[0] / D_IN;   // 100000
    const int E  = in_sizes[1] / 2;      // 1600000
    const int* src = ei;
    const int* dst = ei + E;

    // workspace layout
    float* ws = (float*)d_ws;
    float* H      = ws;                          // n*64 floats (layer3 uses n*32)
    float* X2     = H  + (size_t)n * 64;         // n*64 floats
    float* HS     = X2 + (size_t)n * 64;         // n
    float* HD     = HS + n;                      // n
    int*   deg    = (int*)(HD + n);              // n
    int*   cnt    = deg + n;                     // n
    int*   rowptr = cnt + n;                     // n+1
    int*   sums   = rowptr + (n + 1);            // 512
    int*   esrc   = sums + 512;                  // E

    const int NB = (n + 511) / 512;              // scan chunks (196)

    // ---- CSR build (once; graph identical for all 3 layers) ----
    hipMemsetAsync(deg, 0, (size_t)n * 4, stream);
    hipMemsetAsync(cnt, 0, (size_t)n * 4, stream);
    hist_kernel<<<(E + 255) / 256, 256, 0, stream>>>(dst, deg, E);
    scan_phase1<<<NB, 512, 0, stream>>>(deg, rowptr, sums, n);
    scan_phase2<<<1, 512, 0, stream>>>(sums, NB);
    scan_phase3<<<(n + 256) / 256, 256, 0, stream>>>(rowptr, sums, n, E);
    scatter_kernel<<<(E + 255) / 256, 256, 0, stream>>>(src, dst, rowptr, cnt, esrc, E);

    const int gemm_grid = (n + 63) / 64;
    const int ag64_grid = (int)(((size_t)n * 64 + 255) / 256);
    const int ag32_grid = (int)(((size_t)n * 32 + 255) / 256);

    // ---- Layer 1: GATConv(128->64) + BN + ReLU ----
    gemm_scores<128, 64><<<gemm_grid, 256, 0, stream>>>(x, W1, as1, ad1, H, HS, HD, n);
    gat_aggregate<64, true><<<ag64_grid, 256, 0, stream>>>(
        rowptr, esrc, H, HS, HD, b1, g1, be1, rm1, rv1, X2, n);

    // ---- Layer 2: GATConv(64->64) + BN + ReLU ----
    gemm_scores<64, 64><<<gemm_grid, 256, 0, stream>>>(X2, W2, as2, ad2, H, HS, HD, n);
    gat_aggregate<64, true><<<ag64_grid, 256, 0, stream>>>(
        rowptr, esrc, H, HS, HD, b2, g2, be2, rm2, rv2, X2, n);

    // ---- Layer 3: GATConv(64->32), bias only ----
    gemm_scores<64, 32><<<gemm_grid, 256, 0, stream>>>(X2, W3, as3, ad3, H, HS, HD, n);
    gat_aggregate<32, false><<<ag32_grid, 256, 0, stream>>>(
        rowptr, esrc, H, HS, HD, b3, nullptr, nullptr, nullptr, nullptr,
        (float*)d_out, n);
}

// Round 12
// 587.116 us; speedup vs baseline: 2.4763x; 1.0024x over previous
//
#include <hip/hip_runtime.h>

// GAT 3-layer: GATConv(128->64)+BN+ReLU -> GATConv(64->64)+BN+ReLU -> GATConv(64->32)
// fp32. N=100000, E=1600000 (+N implicit self loops).
//
// CSR-by-dst once per launch; per-layer GEMM(+score dots) -> gat_aggregate.
// R11 counters: scatter_kernel #1 (118us, WRITE 107MB = esrc line write-
// allocate amplification, VALU 0.4%). This round: destructive-cursor scatter
// (no cnt array, no rowptr read), int4 edge reads, aggregate unroll x8.

#define D_IN 128
#define EPS 1e-5f
#define SLOPE 0.2f

// ---------------------------------------------------------------------------
// GEMM H = X[n,K] @ W[K,F], fused epilogue: HS = H·a_s, HD = H·a_d per row.
// ---------------------------------------------------------------------------
template <int K, int F>
__global__ __launch_bounds__(256) void gemm_scores(
    const float* __restrict__ X, const float* __restrict__ W,
    const float* __restrict__ a_s, const float* __restrict__ a_d,
    float* __restrict__ H, float* __restrict__ HS, float* __restrict__ HD,
    int n)
{
    constexpr int XS  = (K == 128) ? K : (K + 4);
    constexpr int CPT = F / 16;
    __shared__ float Xs[64 * XS];
    __shared__ float Ws[K * F];

    const int tid  = threadIdx.x;
    const int row0 = blockIdx.x * 64;

    for (int i = tid * 4; i < 64 * K; i += 256 * 4) {
        int row = i / K, col = i % K;
        float4 v = make_float4(0.f, 0.f, 0.f, 0.f);
        if (row0 + row < n)
            v = *(const float4*)&X[(size_t)(row0 + row) * K + col];
        *(float4*)&Xs[row * XS + col] = v;
    }
    for (int i = tid; i < K * F / 4; i += 256)
        *(float4*)&Ws[i * 4] = ((const float4*)W)[i];
    __syncthreads();

    const int tr = tid >> 4, tc = tid & 15;
    float acc[4][CPT];
    #pragma unroll
    for (int i = 0; i < 4; i++)
        #pragma unroll
        for (int j = 0; j < CPT; j++) acc[i][j] = 0.f;

    for (int k = 0; k < K; k += 4) {
        float xv[4][4];
        #pragma unroll
        for (int i = 0; i < 4; i++) {
            float4 t = *(const float4*)&Xs[(tr + 16 * i) * XS + k];
            xv[i][0] = t.x; xv[i][1] = t.y; xv[i][2] = t.z; xv[i][3] = t.w;
        }
        #pragma unroll
        for (int kk = 0; kk < 4; kk++) {
            float wv[CPT];
            if constexpr (CPT == 4) {
                float4 t = *(const float4*)&Ws[(k + kk) * F + tc * 4];
                wv[0] = t.x; wv[1] = t.y; wv[2] = t.z; wv[3] = t.w;
            } else {
                float2 t = *(const float2*)&Ws[(k + kk) * F + tc * 2];
                wv[0] = t.x; wv[1] = t.y;
            }
            #pragma unroll
            for (int i = 0; i < 4; i++)
                #pragma unroll
                for (int j = 0; j < CPT; j++)
                    acc[i][j] += xv[i][kk] * wv[j];
        }
    }

    float cs[CPT], cd[CPT];
    #pragma unroll
    for (int j = 0; j < CPT; j++) {
        cs[j] = a_s[tc * CPT + j];
        cd[j] = a_d[tc * CPT + j];
    }
    #pragma unroll
    for (int i = 0; i < 4; i++) {
        int row = row0 + tr + 16 * i;
        float vs = 0.f, vd = 0.f;
        #pragma unroll
        for (int j = 0; j < CPT; j++) { vs += acc[i][j] * cs[j]; vd += acc[i][j] * cd[j]; }
        #pragma unroll
        for (int m = 1; m < 16; m <<= 1) {
            vs += __shfl_xor(vs, m, 64);
            vd += __shfl_xor(vd, m, 64);
        }
        if (row < n) {
            if constexpr (CPT == 4) {
                float4 t = make_float4(acc[i][0], acc[i][1], acc[i][2], acc[i][3]);
                *(float4*)&H[(size_t)row * F + tc * 4] = t;
            } else {
                float2 t = make_float2(acc[i][0], acc[i][1]);
                *(float2*)&H[(size_t)row * F + tc * 2] = t;
            }
            if (tc == 0) { HS[row] = vs; HD[row] = vd; }
        }
    }
}

// ---------------------------------------------------------------------------
// CSR build: histogram (int4 reads) -> exclusive scan -> destructive-cursor
// scatter (atomicAdd on rowptr itself returns the slot; afterwards rowptr[d]
// = segment END of d, so beg(d) = d ? rowptr[d-1] : 0).
// ---------------------------------------------------------------------------
__global__ __launch_bounds__(256) void hist_kernel(
    const int* __restrict__ dst, int* __restrict__ deg, int E)
{
    int e4 = (blockIdx.x * 256 + threadIdx.x) * 4;
    if (e4 + 3 < E) {
        int4 d4 = *(const int4*)&dst[e4];
        atomicAdd(&deg[d4.x], 1);
        atomicAdd(&deg[d4.y], 1);
        atomicAdd(&deg[d4.z], 1);
        atomicAdd(&deg[d4.w], 1);
    } else {
        for (int e = e4; e < E; ++e) atomicAdd(&deg[dst[e]], 1);
    }
}

__global__ __launch_bounds__(512) void scan_phase1(
    const int* __restrict__ deg, int* __restrict__ rowptr,
    int* __restrict__ sums, int n)
{
    __shared__ int s[512];
    int t = threadIdx.x;
    int i = blockIdx.x * 512 + t;
    int v = (i < n) ? deg[i] : 0;
    s[t] = v;
    __syncthreads();
    for (int off = 1; off < 512; off <<= 1) {
        int x = (t >= off) ? s[t - off] : 0;
        __syncthreads();
        s[t] += x;
        __syncthreads();
    }
    if (i < n) rowptr[i] = s[t] - v;              // exclusive within chunk
    if (t == 511) sums[blockIdx.x] = s[511];      // chunk total
}

__global__ __launch_bounds__(512) void scan_phase2(int* __restrict__ sums, int nb)
{
    __shared__ int s[512];
    int t = threadIdx.x;
    int v = (t < nb) ? sums[t] : 0;
    s[t] = v;
    __syncthreads();
    for (int off = 1; off < 512; off <<= 1) {
        int x = (t >= off) ? s[t - off] : 0;
        __syncthreads();
        s[t] += x;
        __syncthreads();
    }
    if (t < nb) sums[t] = s[t] - v;               // exclusive chunk offsets
}

__global__ __launch_bounds__(256) void scan_phase3(
    int* __restrict__ rowptr, const int* __restrict__ sums, int n, int E)
{
    int i = blockIdx.x * 256 + threadIdx.x;
    if (i < n) rowptr[i] += sums[i >> 9];
    else if (i == n) rowptr[n] = E;
}

__global__ __launch_bounds__(256) void scatter_kernel(
    const int* __restrict__ src, const int* __restrict__ dst,
    int* __restrict__ rowptr /*destructive cursor*/,
    int* __restrict__ esrc, int E)
{
    int e4 = (blockIdx.x * 256 + threadIdx.x) * 4;
    if (e4 + 3 < E) {
        int4 s4 = *(const int4*)&src[e4];
        int4 d4 = *(const int4*)&dst[e4];
        esrc[atomicAdd(&rowptr[d4.x], 1)] = s4.x;
        esrc[atomicAdd(&rowptr[d4.y], 1)] = s4.y;
        esrc[atomicAdd(&rowptr[d4.z], 1)] = s4.z;
        esrc[atomicAdd(&rowptr[d4.w], 1)] = s4.w;
    } else {
        for (int e = e4; e < E; ++e)
            esrc[atomicAdd(&rowptr[dst[e]], 1)] = src[e];
    }
}

// ---------------------------------------------------------------------------
// Fused GAT aggregation, unrolled x8 (+x4 +scalar tail) for MLP.
//   rowptr is POST-destructive-scatter: rowptr[d] = end(d), beg = rowptr[d-1].
// ---------------------------------------------------------------------------
template <int F, bool BN>
__global__ __launch_bounds__(256) void gat_aggregate(
    const int* __restrict__ rowptr, const int* __restrict__ esrc,
    const float* __restrict__ H, const float* __restrict__ HS,
    const float* __restrict__ HD,
    const float* __restrict__ b, const float* __restrict__ g,
    const float* __restrict__ be, const float* __restrict__ rm,
    const float* __restrict__ rv,
    float* __restrict__ OUT, int n)
{
    int t = blockIdx.x * 256 + threadIdx.x;
    int node = t / F, f = t % F;          // F is a power of two -> shifts
    if (node >= n) return;

    float hd = HD[node];
    // self loop seeds the accumulator
    float sc = HS[node] + hd;
    sc = sc > 0.f ? sc : SLOPE * sc;
    float p = __expf(sc);
    float s = p;
    float acc = p * H[(size_t)node * F + f];

    const int beg = node ? rowptr[node - 1] : 0;
    const int end = rowptr[node];
    int j = beg;
    const int len = end - beg;

    // ---- 8-wide batches ----
    const int end8 = beg + (len & ~7);
    for (; j < end8; j += 8) {
        int   sr[8];
        float a[8], h[8];
        #pragma unroll
        for (int u = 0; u < 8; ++u) sr[u] = esrc[j + u];
        #pragma unroll
        for (int u = 0; u < 8; ++u) a[u] = HS[sr[u]];
        #pragma unroll
        for (int u = 0; u < 8; ++u) h[u] = H[(size_t)sr[u] * F + f];
        #pragma unroll
        for (int u = 0; u < 8; ++u) {
            float e2 = a[u] + hd;
            e2 = e2 > 0.f ? e2 : SLOPE * e2;
            float p2 = __expf(e2);
            s   += p2;
            acc += p2 * h[u];
        }
    }
    // ---- 4-wide batch ----
    if (len & 4) {
        int   sr[4];
        float a[4], h[4];
        #pragma unroll
        for (int u = 0; u < 4; ++u) sr[u] = esrc[j + u];
        #pragma unroll
        for (int u = 0; u < 4; ++u) a[u] = HS[sr[u]];
        #pragma unroll
        for (int u = 0; u < 4; ++u) h[u] = H[(size_t)sr[u] * F + f];
        #pragma unroll
        for (int u = 0; u < 4; ++u) {
            float e2 = a[u] + hd;
            e2 = e2 > 0.f ? e2 : SLOPE * e2;
            float p2 = __expf(e2);
            s   += p2;
            acc += p2 * h[u];
        }
        j += 4;
    }
    // ---- scalar tail ----
    for (; j < end; ++j) {
        int sr = esrc[j];
        float e2 = HS[sr] + hd;
        e2 = e2 > 0.f ? e2 : SLOPE * e2;
        float p2 = __expf(e2);
        s += p2;
        acc += p2 * H[(size_t)sr * F + f];
    }

    float v = acc / s + b[f];
    if constexpr (BN) {
        v = (v - rm[f]) * rsqrtf(rv[f] + EPS) * g[f] + be[f];
        v = v > 0.f ? v : 0.f;
    }
    OUT[(size_t)node * F + f] = v;
}

// ---------------------------------------------------------------------------
extern "C" void kernel_launch(void* const* d_in, const int* in_sizes, int n_in,
                              void* d_out, int out_size, void* d_ws, size_t ws_size,
                              hipStream_t stream)
{
    const float* x   = (const float*)d_in[0];
    const int*   ei  = (const int*)d_in[1];
    const float* W1  = (const float*)d_in[2];
    const float* as1 = (const float*)d_in[3];
    const float* ad1 = (const float*)d_in[4];
    const float* b1  = (const float*)d_in[5];
    const float* g1  = (const float*)d_in[6];
    const float* be1 = (const float*)d_in[7];
    const float* rm1 = (const float*)d_in[8];
    const float* rv1 = (const float*)d_in[9];
    const float* W2  = (const float*)d_in[10];
    const float* as2 = (const float*)d_in[11];
    const float* ad2 = (const float*)d_in[12];
    const float* b2  = (const float*)d_in[13];
    const float* g2  = (const float*)d_in[14];
    const float* be2 = (const float*)d_in[15];
    const float* rm2 = (const float*)d_in[16];
    const float* rv2 = (const float*)d_in[17];
    const float* W3  = (const float*)d_in[18];
    const float* as3 = (const float*)d_in[19];
    const float* ad3 = (const float*)d_in[20];
    const float* b3  = (const float*)d_in[21];

    const int n  = in_sizes[0] / D_IN;   // 100000
    const int E  = in_sizes[1] / 2;      // 1600000
    const int* src = ei;
    const int* dst = ei + E;

    // workspace layout (cnt removed)
    float* ws = (float*)d_ws;
    float* H      = ws;                          // n*64 floats (layer3 uses n*32)
    float* X2     = H  + (size_t)n * 64;         // n*64 floats
    float* HS     = X2 + (size_t)n * 64;         // n
    float* HD     = HS + n;                      // n
    int*   deg    = (int*)(HD + n);              // n
    int*   rowptr = deg + n;                     // n+1
    int*   sums   = rowptr + (n + 1);            // 512
    int*   esrc   = sums + 512;                  // E

    const int NB = (n + 511) / 512;              // scan chunks (196)
    const int e4_grid = (E / 4 + 255) / 256;

    // ---- CSR build (once; graph identical for all 3 layers) ----
    hipMemsetAsync(deg, 0, (size_t)n * 4, stream);
    hist_kernel<<<e4_grid, 256, 0, stream>>>(dst, deg, E);
    scan_phase1<<<NB, 512, 0, stream>>>(deg, rowptr, sums, n);
    scan_phase2<<<1, 512, 0, stream>>>(sums, NB);
    scan_phase3<<<(n + 256) / 256, 256, 0, stream>>>(rowptr, sums, n, E);
    scatter_kernel<<<e4_grid, 256, 0, stream>>>(src, dst, rowptr, esrc, E);
    // after scatter: rowptr[d] = end(d); beg(d) = d ? rowptr[d-1] : 0

    const int gemm_grid = (n + 63) / 64;
    const int ag64_grid = (int)(((size_t)n * 64 + 255) / 256);
    const int ag32_grid = (int)(((size_t)n * 32 + 255) / 256);

    // ---- Layer 1: GATConv(128->64) + BN + ReLU ----
    gemm_scores<128, 64><<<gemm_grid, 256, 0, stream>>>(x, W1, as1, ad1, H, HS, HD, n);
    gat_aggregate<64, true><<<ag64_grid, 256, 0, stream>>>(
        rowptr, esrc, H, HS, HD, b1, g1, be1, rm1, rv1, X2, n);

    // ---- Layer 2: GATConv(64->64) + BN + ReLU ----
    gemm_scores<64, 64><<<gemm_grid, 256, 0, stream>>>(X2, W2, as2, ad2, H, HS, HD, n);
    gat_aggregate<64, true><<<ag64_grid, 256, 0, stream>>>(
        rowptr, esrc, H, HS, HD, b2, g2, be2, rm2, rv2, X2, n);

    // ---- Layer 3: GATConv(64->32), bias only ----
    gemm_scores<64, 32><<<gemm_grid, 256, 0, stream>>>(X2, W3, as3, ad3, H, HS, HD, n);
    gat_aggregate<32, false><<<ag32_grid, 256, 0, stream>>>(
        rowptr, esrc, H, HS, HD, b3, nullptr, nullptr, nullptr, nullptr,
        (float*)d_out, n);
}

// Round 13
// 503.142 us; speedup vs baseline: 2.8896x; 1.1669x over previous
//
#include <hip/hip_runtime.h>

// GAT 3-layer: GATConv(128->64)+BN+ReLU -> GATConv(64->64)+BN+ReLU -> GATConv(64->32)
// fp32. N=100000, E=1600000 (+N implicit self loops).
//
// R12 counters: scatter 127us, WRITE 108MB = line-granular write-allocate
// amplification (1.6M random 4B stores). This round: two-pass binned scatter
// (bucket = dst>>9): pass1 LDS-sorts 4096-edge chunks into per-bucket runs
// (coalesced), pass2 scatters within one bucket via LDS staging (coalesced).
// All CSR writes now line-contiguous.

#define D_IN 128
#define EPS 1e-5f
#define SLOPE 0.2f

// ---------------------------------------------------------------------------
// GEMM H = X[n,K] @ W[K,F], fused epilogue: HS = H·a_s, HD = H·a_d per row.
// ---------------------------------------------------------------------------
template <int K, int F>
__global__ __launch_bounds__(256) void gemm_scores(
    const float* __restrict__ X, const float* __restrict__ W,
    const float* __restrict__ a_s, const float* __restrict__ a_d,
    float* __restrict__ H, float* __restrict__ HS, float* __restrict__ HD,
    int n)
{
    constexpr int XS  = (K == 128) ? K : (K + 4);
    constexpr int CPT = F / 16;
    __shared__ float Xs[64 * XS];
    __shared__ float Ws[K * F];

    const int tid  = threadIdx.x;
    const int row0 = blockIdx.x * 64;

    for (int i = tid * 4; i < 64 * K; i += 256 * 4) {
        int row = i / K, col = i % K;
        float4 v = make_float4(0.f, 0.f, 0.f, 0.f);
        if (row0 + row < n)
            v = *(const float4*)&X[(size_t)(row0 + row) * K + col];
        *(float4*)&Xs[row * XS + col] = v;
    }
    for (int i = tid; i < K * F / 4; i += 256)
        *(float4*)&Ws[i * 4] = ((const float4*)W)[i];
    __syncthreads();

    const int tr = tid >> 4, tc = tid & 15;
    float acc[4][CPT];
    #pragma unroll
    for (int i = 0; i < 4; i++)
        #pragma unroll
        for (int j = 0; j < CPT; j++) acc[i][j] = 0.f;

    for (int k = 0; k < K; k += 4) {
        float xv[4][4];
        #pragma unroll
        for (int i = 0; i < 4; i++) {
            float4 t = *(const float4*)&Xs[(tr + 16 * i) * XS + k];
            xv[i][0] = t.x; xv[i][1] = t.y; xv[i][2] = t.z; xv[i][3] = t.w;
        }
        #pragma unroll
        for (int kk = 0; kk < 4; kk++) {
            float wv[CPT];
            if constexpr (CPT == 4) {
                float4 t = *(const float4*)&Ws[(k + kk) * F + tc * 4];
                wv[0] = t.x; wv[1] = t.y; wv[2] = t.z; wv[3] = t.w;
            } else {
                float2 t = *(const float2*)&Ws[(k + kk) * F + tc * 2];
                wv[0] = t.x; wv[1] = t.y;
            }
            #pragma unroll
            for (int i = 0; i < 4; i++)
                #pragma unroll
                for (int j = 0; j < CPT; j++)
                    acc[i][j] += xv[i][kk] * wv[j];
        }
    }

    float cs[CPT], cd[CPT];
    #pragma unroll
    for (int j = 0; j < CPT; j++) {
        cs[j] = a_s[tc * CPT + j];
        cd[j] = a_d[tc * CPT + j];
    }
    #pragma unroll
    for (int i = 0; i < 4; i++) {
        int row = row0 + tr + 16 * i;
        float vs = 0.f, vd = 0.f;
        #pragma unroll
        for (int j = 0; j < CPT; j++) { vs += acc[i][j] * cs[j]; vd += acc[i][j] * cd[j]; }
        #pragma unroll
        for (int m = 1; m < 16; m <<= 1) {
            vs += __shfl_xor(vs, m, 64);
            vd += __shfl_xor(vd, m, 64);
        }
        if (row < n) {
            if constexpr (CPT == 4) {
                float4 t = make_float4(acc[i][0], acc[i][1], acc[i][2], acc[i][3]);
                *(float4*)&H[(size_t)row * F + tc * 4] = t;
            } else {
                float2 t = make_float2(acc[i][0], acc[i][1]);
                *(float2*)&H[(size_t)row * F + tc * 2] = t;
            }
            if (tc == 0) { HS[row] = vs; HD[row] = vd; }
        }
    }
}

// ---------------------------------------------------------------------------
// CSR build.
// ---------------------------------------------------------------------------
__global__ __launch_bounds__(256) void hist_kernel(
    const int* __restrict__ dst, int* __restrict__ deg, int E)
{
    int e4 = (blockIdx.x * 256 + threadIdx.x) * 4;
    if (e4 + 3 < E) {
        int4 d4 = *(const int4*)&dst[e4];
        atomicAdd(&deg[d4.x], 1);
        atomicAdd(&deg[d4.y], 1);
        atomicAdd(&deg[d4.z], 1);
        atomicAdd(&deg[d4.w], 1);
    } else {
        for (int e = e4; e < E; ++e) atomicAdd(&deg[dst[e]], 1);
    }
}

__global__ __launch_bounds__(512) void scan_phase1(
    const int* __restrict__ deg, int* __restrict__ rowptr,
    int* __restrict__ sums, int n)
{
    __shared__ int s[512];
    int t = threadIdx.x;
    int i = blockIdx.x * 512 + t;
    int v = (i < n) ? deg[i] : 0;
    s[t] = v;
    __syncthreads();
    for (int off = 1; off < 512; off <<= 1) {
        int x = (t >= off) ? s[t - off] : 0;
        __syncthreads();
        s[t] += x;
        __syncthreads();
    }
    if (i < n) rowptr[i] = s[t] - v;              // exclusive within chunk
    if (t == 511) sums[blockIdx.x] = s[511];      // chunk total
}

__global__ __launch_bounds__(512) void scan_phase2(int* __restrict__ sums, int nb)
{
    __shared__ int s[512];
    int t = threadIdx.x;
    int v = (t < nb) ? sums[t] : 0;
    s[t] = v;
    __syncthreads();
    for (int off = 1; off < 512; off <<= 1) {
        int x = (t >= off) ? s[t - off] : 0;
        __syncthreads();
        s[t] += x;
        __syncthreads();
    }
    if (t < nb) sums[t] = s[t] - v;               // exclusive chunk offsets
}

__global__ __launch_bounds__(256) void scan_phase3(
    int* __restrict__ rowptr, const int* __restrict__ sums, int n, int E)
{
    int i = blockIdx.x * 256 + threadIdx.x;
    if (i < n) rowptr[i] += sums[i >> 9];
    else if (i == n) rowptr[n] = E;
}

// bucket b covers nodes [b*512,(b+1)*512); its CSR region = rowptr range.
__global__ __launch_bounds__(256) void bcur_init(
    const int* __restrict__ rowptr, int* __restrict__ bcur, int n, int B)
{
    int b = blockIdx.x * 256 + threadIdx.x;
    if (b < B) {
        int nb = b << 9;
        if (nb > n) nb = n;
        bcur[b] = rowptr[nb];
    }
}

// ---------------------------------------------------------------------------
// Pass 1: bin 4096-edge chunks into per-bucket runs via LDS local sort.
// Packed edge: (dst&511)<<17 | src  (src<2^17, local<2^9).
// ---------------------------------------------------------------------------
#define CHUNK 4096
#define NBKT  256   // array size; actual buckets B=196

__global__ __launch_bounds__(256) void bin_kernel(
    const int* __restrict__ src, const int* __restrict__ dst,
    int* __restrict__ bcur, int* __restrict__ binned, int E)
{
    __shared__ int2 stage[CHUNK];          // (packed, bucket)
    __shared__ int cnt[NBKT], loff[NBKT], lcur[NBKT], shift[NBKT];

    const int tid  = threadIdx.x;
    const int base = blockIdx.x * CHUNK;
    const int ccnt = min(CHUNK, E - base);           // edges in this chunk

    if (tid < NBKT) { cnt[tid] = 0; }
    __syncthreads();

    // load up to 16 edges/thread, histogram buckets
    int es[16], ed[16];
    const int tb = base + tid * 16;
    const int tm = max(0, min(16, E - tb));
    #pragma unroll 4
    for (int k = 0; k < 16; ++k) {
        if (k < tm) {
            es[k] = src[tb + k];
            ed[k] = dst[tb + k];
            atomicAdd(&cnt[ed[k] >> 9], 1);
        }
    }
    __syncthreads();

    // exclusive scan of cnt (Hillis-Steele over 256)
    loff[tid] = cnt[tid];
    __syncthreads();
    for (int off = 1; off < NBKT; off <<= 1) {
        int x = (tid >= off) ? loff[tid - off] : 0;
        __syncthreads();
        loff[tid] += x;
        __syncthreads();
    }
    int excl = loff[tid] - cnt[tid];
    __syncthreads();
    loff[tid] = excl;
    lcur[tid] = 0;
    // reserve global run for each bucket
    if (cnt[tid] > 0) {
        int g = atomicAdd(&bcur[tid], cnt[tid]);
        shift[tid] = g - excl;
    }
    __syncthreads();

    // place edges into LDS, sorted by bucket
    #pragma unroll 4
    for (int k = 0; k < 16; ++k) {
        if (k < tm) {
            int b = ed[k] >> 9;
            int pos = loff[b] + atomicAdd(&lcur[b], 1);
            stage[pos] = make_int2(((ed[k] & 511) << 17) | es[k], b);
        }
    }
    __syncthreads();

    // write out: consecutive LDS positions -> consecutive global within runs
    for (int i = tid; i < ccnt; i += 256) {
        int2 v = stage[i];
        binned[shift[v.y] + i] = v.x;
    }
}

// ---------------------------------------------------------------------------
// Pass 2: within-bucket scatter via LDS staging; coalesced in and out.
// Bucket b region = [rowptr[b*512], rowptr[min(n,(b+1)*512)]).
// ---------------------------------------------------------------------------
#define CAP 12288   // LDS staging capacity (avg bucket = 8192, ~24 sigma slack)

__global__ __launch_bounds__(256) void bucket_scatter(
    const int* __restrict__ rowptr, const int* __restrict__ binned,
    int* __restrict__ esrc, int n)
{
    __shared__ int outbuf[CAP];
    __shared__ int cur[512];

    const int tid  = threadIdx.x;
    const int b    = blockIdx.x;
    const int nb   = b << 9;
    const int ne   = min(n, nb + 512);
    const int nn   = ne - nb;
    const int sbeg = rowptr[nb];
    const int send = rowptr[ne];
    const int cnt  = send - sbeg;

    for (int l = tid; l < nn; l += 256)
        cur[l] = rowptr[nb + l] - sbeg;
    __syncthreads();

    if (cnt <= CAP) {
        for (int i = sbeg + tid; i < send; i += 256) {
            int v = binned[i];
            int slot = atomicAdd(&cur[v >> 17], 1);
            outbuf[slot] = v & 0x1FFFF;
        }
        __syncthreads();
        for (int i = tid; i < cnt; i += 256)
            esrc[sbeg + i] = outbuf[i];
    } else {
        // overflow fallback (statistically unreachable): direct scatter
        for (int i = sbeg + tid; i < send; i += 256) {
            int v = binned[i];
            int slot = atomicAdd(&cur[v >> 17], 1);
            esrc[sbeg + slot] = v & 0x1FFFF;
        }
    }
}

// ---------------------------------------------------------------------------
// Fused GAT aggregation, unrolled x8 (+x4 +scalar tail).
// ---------------------------------------------------------------------------
template <int F, bool BN>
__global__ __launch_bounds__(256) void gat_aggregate(
    const int* __restrict__ rowptr, const int* __restrict__ esrc,
    const float* __restrict__ H, const float* __restrict__ HS,
    const float* __restrict__ HD,
    const float* __restrict__ b, const float* __restrict__ g,
    const float* __restrict__ be, const float* __restrict__ rm,
    const float* __restrict__ rv,
    float* __restrict__ OUT, int n)
{
    int t = blockIdx.x * 256 + threadIdx.x;
    int node = t / F, f = t % F;
    if (node >= n) return;

    float hd = HD[node];
    float sc = HS[node] + hd;
    sc = sc > 0.f ? sc : SLOPE * sc;
    float p = __expf(sc);
    float s = p;
    float acc = p * H[(size_t)node * F + f];

    const int beg = rowptr[node];
    const int end = rowptr[node + 1];
    int j = beg;
    const int len = end - beg;

    const int end8 = beg + (len & ~7);
    for (; j < end8; j += 8) {
        int   sr[8];
        float a[8], h[8];
        #pragma unroll
        for (int u = 0; u < 8; ++u) sr[u] = esrc[j + u];
        #pragma unroll
        for (int u = 0; u < 8; ++u) a[u] = HS[sr[u]];
        #pragma unroll
        for (int u = 0; u < 8; ++u) h[u] = H[(size_t)sr[u] * F + f];
        #pragma unroll
        for (int u = 0; u < 8; ++u) {
            float e2 = a[u] + hd;
            e2 = e2 > 0.f ? e2 : SLOPE * e2;
            float p2 = __expf(e2);
            s   += p2;
            acc += p2 * h[u];
        }
    }
    if (len & 4) {
        int   sr[4];
        float a[4], h[4];
        #pragma unroll
        for (int u = 0; u < 4; ++u) sr[u] = esrc[j + u];
        #pragma unroll
        for (int u = 0; u < 4; ++u) a[u] = HS[sr[u]];
        #pragma unroll
        for (int u = 0; u < 4; ++u) h[u] = H[(size_t)sr[u] * F + f];
        #pragma unroll
        for (int u = 0; u < 4; ++u) {
            float e2 = a[u] + hd;
            e2 = e2 > 0.f ? e2 : SLOPE * e2;
            float p2 = __expf(e2);
            s   += p2;
            acc += p2 * h[u];
        }
        j += 4;
    }
    for (; j < end; ++j) {
        int sr = esrc[j];
        float e2 = HS[sr] + hd;
        e2 = e2 > 0.f ? e2 : SLOPE * e2;
        float p2 = __expf(e2);
        s += p2;
        acc += p2 * H[(size_t)sr * F + f];
    }

    float v = acc / s + b[f];
    if constexpr (BN) {
        v = (v - rm[f]) * rsqrtf(rv[f] + EPS) * g[f] + be[f];
        v = v > 0.f ? v : 0.f;
    }
    OUT[(size_t)node * F + f] = v;
}

// ---------------------------------------------------------------------------
extern "C" void kernel_launch(void* const* d_in, const int* in_sizes, int n_in,
                              void* d_out, int out_size, void* d_ws, size_t ws_size,
                              hipStream_t stream)
{
    const float* x   = (const float*)d_in[0];
    const int*   ei  = (const int*)d_in[1];
    const float* W1  = (const float*)d_in[2];
    const float* as1 = (const float*)d_in[3];
    const float* ad1 = (const float*)d_in[4];
    const float* b1  = (const float*)d_in[5];
    const float* g1  = (const float*)d_in[6];
    const float* be1 = (const float*)d_in[7];
    const float* rm1 = (const float*)d_in[8];
    const float* rv1 = (const float*)d_in[9];
    const float* W2  = (const float*)d_in[10];
    const float* as2 = (const float*)d_in[11];
    const float* ad2 = (const float*)d_in[12];
    const float* b2  = (const float*)d_in[13];
    const float* g2  = (const float*)d_in[14];
    const float* be2 = (const float*)d_in[15];
    const float* rm2 = (const float*)d_in[16];
    const float* rv2 = (const float*)d_in[17];
    const float* W3  = (const float*)d_in[18];
    const float* as3 = (const float*)d_in[19];
    const float* ad3 = (const float*)d_in[20];
    const float* b3  = (const float*)d_in[21];

    const int n  = in_sizes[0] / D_IN;   // 100000
    const int E  = in_sizes[1] / 2;      // 1600000
    const int* src = ei;
    const int* dst = ei + E;
    const int B  = (n + 511) >> 9;       // 196 buckets

    // workspace layout
    float* ws = (float*)d_ws;
    float* H      = ws;                          // n*64 floats
    float* X2     = H  + (size_t)n * 64;         // n*64 floats
    float* HS     = X2 + (size_t)n * 64;         // n
    float* HD     = HS + n;                      // n
    int*   deg    = (int*)(HD + n);              // n
    int*   rowptr = deg + n;                     // n+1
    int*   sums   = rowptr + (n + 1);            // 512
    int*   esrc   = sums + 512;                  // E
    int*   bcur   = esrc + E;                    // 256
    int*   binned = (int*)X2;                    // E ints, aliases X2 (dead
                                                 // until aggregate-1 writes)

    const int NB = (n + 511) / 512;              // scan chunks (196)

    // ---- CSR build (once; graph identical for all 3 layers) ----
    hipMemsetAsync(deg, 0, (size_t)n * 4, stream);
    hist_kernel<<<(E / 4 + 255) / 256, 256, 0, stream>>>(dst, deg, E);
    scan_phase1<<<NB, 512, 0, stream>>>(deg, rowptr, sums, n);
    scan_phase2<<<1, 512, 0, stream>>>(sums, NB);
    scan_phase3<<<(n + 256) / 256, 256, 0, stream>>>(rowptr, sums, n, E);
    bcur_init<<<1, 256, 0, stream>>>(rowptr, bcur, n, B);
    bin_kernel<<<(E + CHUNK - 1) / CHUNK, 256, 0, stream>>>(src, dst, bcur, binned, E);
    bucket_scatter<<<B, 256, 0, stream>>>(rowptr, binned, esrc, n);

    const int gemm_grid = (n + 63) / 64;
    const int ag64_grid = (int)(((size_t)n * 64 + 255) / 256);
    const int ag32_grid = (int)(((size_t)n * 32 + 255) / 256);

    // ---- Layer 1: GATConv(128->64) + BN + ReLU ----
    gemm_scores<128, 64><<<gemm_grid, 256, 0, stream>>>(x, W1, as1, ad1, H, HS, HD, n);
    gat_aggregate<64, true><<<ag64_grid, 256, 0, stream>>>(
        rowptr, esrc, H, HS, HD, b1, g1, be1, rm1, rv1, X2, n);

    // ---- Layer 2: GATConv(64->64) + BN + ReLU ----
    gemm_scores<64, 64><<<gemm_grid, 256, 0, stream>>>(X2, W2, as2, ad2, H, HS, HD, n);
    gat_aggregate<64, true><<<ag64_grid, 256, 0, stream>>>(
        rowptr, esrc, H, HS, HD, b2, g2, be2, rm2, rv2, X2, n);

    // ---- Layer 3: GATConv(64->32), bias only ----
    gemm_scores<64, 32><<<gemm_grid, 256, 0, stream>>>(X2, W3, as3, ad3, H, HS, HD, n);
    gat_aggregate<32, false><<<ag32_grid, 256, 0, stream>>>(
        rowptr, esrc, H, HS, HD, b3, nullptr, nullptr, nullptr, nullptr,
        (float*)d_out, n);
}